// Round 2
// baseline (319.634 us; speedup 1.0000x reference)
//
#include <hip/hip_runtime.h>

#define BB    8
#define CC    64
#define NN    2048
#define GG    2048
#define MFREQ 4032

typedef __attribute__((ext_vector_type(4))) float f32x4;
typedef __attribute__((ext_vector_type(8))) short bf16x8;

static __device__ __forceinline__ unsigned short f2bf(float f) {
    union { float f; unsigned u; } v; v.f = f;
    unsigned r = v.u + 0x7fff + ((v.u >> 16) & 1);   // RNE
    return (unsigned short)(r >> 16);
}

#define ASYNC_COPY16(gp, lp)                                                        \
    __builtin_amdgcn_global_load_lds(                                               \
        (const __attribute__((address_space(1))) unsigned int*)(gp),                \
        (__attribute__((address_space(3))) unsigned int*)(lp), 16, 0, 0)

// ---------------------------------------------------------------------------
// Fused streaming packs. Each thread: 2 groups of 8 bf16; each group is ONE
// uint4 (16B) store fed by TWO float4 loads -> store's dataflow forces >=2
// loads in flight (MLP), full 1KB/wave stores.
//  blocks [0, 2048)    : Af [4096 x 2048]   (512 groups/block)
//  blocks [2048, 2304) : Xb [512 x 2048]
//  blocks [2304, 6400) : Mi [2048 x 8192]
__global__ __launch_bounds__(256) void pack_all(const float* __restrict__ vf_re,
                                                const float* __restrict__ vf_im,
                                                const float* __restrict__ x,
                                                const float* __restrict__ vi_re,
                                                const float* __restrict__ vi_im,
                                                unsigned short* __restrict__ af,
                                                unsigned short* __restrict__ xb,
                                                unsigned short* __restrict__ mi) {
    int blk = blockIdx.x;
    int t = threadIdx.x;
    float4 v[2][2];
    unsigned short* dst[2];
    if (blk < 2048) {
        #pragma unroll
        for (int u = 0; u < 2; ++u) {
            int gi = blk * 512 + u * 256 + t;
            int m = gi >> 8;                 // 256 groups per 2048-wide row
            int q8 = (gi & 255) * 8;
            int g = m & 2047;
            int f = (g >> 5) * 63 + (g & 31);
            const float* src = (m < 2048 ? vf_re : vf_im) + (size_t)f * 2048 + q8;
            v[u][0] = *(const float4*)src;
            v[u][1] = *(const float4*)(src + 4);
            dst[u] = af + (size_t)m * 2048 + q8;
        }
    } else if (blk < 2304) {
        #pragma unroll
        for (int u = 0; u < 2; ++u) {
            int gi = (blk - 2048) * 512 + u * 256 + t;
            int q8 = gi * 8;
            v[u][0] = *(const float4*)(x + q8);
            v[u][1] = *(const float4*)(x + q8 + 4);
            dst[u] = xb + q8;
        }
    } else {
        #pragma unroll
        for (int u = 0; u < 2; ++u) {
            int gi = (blk - 2304) * 512 + u * 256 + t;
            int n = gi >> 10;                // 1024 groups per 8192-wide row
            int q8 = (gi & 1023) * 8;
            int region = q8 >> 11;
            int off = q8 & 2047;
            if (region == 0) {
                const float* src = vi_re + (size_t)n * MFREQ + off;
                v[u][0] = *(const float4*)src;
                v[u][1] = *(const float4*)(src + 4);
            } else if (region == 1) {
                const float* src = vi_im + (size_t)n * MFREQ + off;
                float4 a = *(const float4*)src;
                float4 b = *(const float4*)(src + 4);
                v[u][0].x = -a.x; v[u][0].y = -a.y; v[u][0].z = -a.z; v[u][0].w = -a.w;
                v[u][1].x = -b.x; v[u][1].y = -b.y; v[u][1].z = -b.z; v[u][1].w = -b.w;
            } else {
                if (off < 64) {
                    v[u][0].x = v[u][0].y = v[u][0].z = v[u][0].w = 0.0f;
                    v[u][1].x = v[u][1].y = v[u][1].z = v[u][1].w = 0.0f;
                } else {
                    // out[off+j] = src[4095 - off - j], j = 0..7
                    const float* src = (region == 2 ? vi_re : vi_im) + (size_t)n * MFREQ;
                    float4 a = *(const float4*)(src + 4092 - off);
                    float4 b = *(const float4*)(src + 4088 - off);
                    v[u][0].x = a.w; v[u][0].y = a.z; v[u][0].z = a.y; v[u][0].w = a.x;
                    v[u][1].x = b.w; v[u][1].y = b.z; v[u][1].z = b.y; v[u][1].w = b.x;
                }
            }
            dst[u] = mi + (size_t)n * 8192 + q8;
        }
    }
    #pragma unroll
    for (int u = 0; u < 2; ++u) {
        uint4 o;
        o.x = (unsigned int)f2bf(v[u][0].x) | ((unsigned int)f2bf(v[u][0].y) << 16);
        o.y = (unsigned int)f2bf(v[u][0].z) | ((unsigned int)f2bf(v[u][0].w) << 16);
        o.z = (unsigned int)f2bf(v[u][1].x) | ((unsigned int)f2bf(v[u][1].y) << 16);
        o.w = (unsigned int)f2bf(v[u][1].z) | ((unsigned int)f2bf(v[u][1].w) << 16);
        *(uint4*)dst[u] = o;
    }
}

// Transpose weights: wt[g][io] = packed bf16 (re | im<<16)
__global__ __launch_bounds__(256) void pack_wt(const float* __restrict__ w1_re,
                                               const float* __restrict__ w1_im,
                                               const float* __restrict__ w2_re,
                                               const float* __restrict__ w2_im,
                                               unsigned int* __restrict__ wt) {
    __shared__ float sre[64][65];
    __shared__ float sim[64][65];
    int wsel = blockIdx.z;
    const float* wre = wsel ? w2_re : w1_re;
    const float* wim = wsel ? w2_im : w1_im;
    int io0 = blockIdx.y * 64, xy0 = blockIdx.x * 64;
    int t = threadIdx.x;
    int r = t >> 2, cq = (t & 3) * 16;
    for (int j = 0; j < 16; j += 4) {
        float4 a = *(const float4*)(wre + (size_t)(io0 + r) * 1024 + xy0 + cq + j);
        float4 b = *(const float4*)(wim + (size_t)(io0 + r) * 1024 + xy0 + cq + j);
        sre[r][cq + j + 0] = a.x; sre[r][cq + j + 1] = a.y; sre[r][cq + j + 2] = a.z; sre[r][cq + j + 3] = a.w;
        sim[r][cq + j + 0] = b.x; sim[r][cq + j + 1] = b.y; sim[r][cq + j + 2] = b.z; sim[r][cq + j + 3] = b.w;
    }
    __syncthreads();
    int iol = t & 63, gq = t >> 6;
    for (int jj = 0; jj < 16; ++jj) {
        int gl = jj * 4 + gq;
        int g = xy0 + gl + wsel * 1024;
        unsigned int o = (unsigned int)f2bf(sre[iol][gl]) | ((unsigned int)f2bf(sim[iol][gl]) << 16);
        wt[(size_t)g * 4096 + io0 + iol] = o;
    }
}

// phi[b][g] = sum_e m{1,2}[xy][e] * emb[b][e]
// One block per g; loop over b so m-rows load once.
__global__ __launch_bounds__(256) void phi_k(const float* __restrict__ m1_re,
                                             const float* __restrict__ m1_im,
                                             const float* __restrict__ m2_re,
                                             const float* __restrict__ m2_im,
                                             const float* __restrict__ emb,
                                             float* __restrict__ phi_re,
                                             float* __restrict__ phi_im) {
    int g = blockIdx.x, e = threadIdx.x;
    int xy = g & 1023;
    const float* mr = (g < 1024 ? m1_re : m2_re) + xy * 256;
    const float* mi = (g < 1024 ? m1_im : m2_im) + xy * 256;
    float vr = mr[e], vi = mi[e];
    __shared__ float sr[4], si[4];
    for (int bb = 0; bb < 8; ++bb) {
        float em = emb[bb * 256 + e];
        float pr = vr * em, pi = vi * em;
        for (int s = 32; s > 0; s >>= 1) { pr += __shfl_down(pr, s); pi += __shfl_down(pi, s); }
        int wid = e >> 6;
        if ((e & 63) == 0) { sr[wid] = pr; si[wid] = pi; }
        __syncthreads();
        if (e == 0) {
            phi_re[bb * 2048 + g] = sr[0] + sr[1] + sr[2] + sr[3];
            phi_im[bb * 2048 + g] = si[0] + si[1] + si[2] + si[3];
        }
        __syncthreads();
    }
}

// ---------------------------------------------------------------------------
// Split-K MFMA GEMM: P[z] = A[M][Kslice] @ B[N][Kslice]^T
// ilv=1 (forward only): store element (rr,cc) at ((rr&2047)*1024 + cc*2 + (rr>>11))
// i.e. O1 interleaved as [g][c][{re,im}] so middle can ds_read_b64 float2.
__global__ __launch_bounds__(256, 2) void gemm_sk(const unsigned short* __restrict__ A,
                                                  const unsigned short* __restrict__ Bm,
                                                  float* __restrict__ P,
                                                  int M, int N, int K, int Kper, int ilv) {
    __shared__ unsigned short As[128 * 64];
    __shared__ unsigned short Bs[128 * 64];
    int t = threadIdx.x;
    int lane = t & 63, w = t >> 6;
    int m0 = blockIdx.y * 128, n0 = blockIdx.x * 128;
    int z = blockIdx.z;
    int kbase = z * Kper;
    int wm = (w >> 1) * 64, wn = (w & 1) * 64;
    int lr = lane & 15, quad = lane >> 4;
    int rsub = lane >> 3, slot = lane & 7;

    f32x4 acc[4][4] = {};

    for (int kk = kbase; kk < kbase + Kper; kk += 64) {
        __syncthreads();
        #pragma unroll
        for (int l = 0; l < 4; ++l) {
            int r = (w * 4 + l) * 8 + rsub;
            int c = slot ^ (r & 7);
            ASYNC_COPY16(A + (size_t)(m0 + r) * K + kk + c * 8, As + r * 64 + slot * 8);
            ASYNC_COPY16(Bm + (size_t)(n0 + r) * K + kk + c * 8, Bs + r * 64 + slot * 8);
        }
        __syncthreads();
        #pragma unroll
        for (int ks = 0; ks < 2; ++ks) {
            bf16x8 af[4], bfr[4];
            #pragma unroll
            for (int i = 0; i < 4; ++i) {
                int row = wm + i * 16 + lr;
                int q = (ks * 4 + quad) ^ (row & 7);
                af[i] = *(const bf16x8*)(As + row * 64 + q * 8);
                int rowb = wn + i * 16 + lr;
                int qb = (ks * 4 + quad) ^ (rowb & 7);
                bfr[i] = *(const bf16x8*)(Bs + rowb * 64 + qb * 8);
            }
            #pragma unroll
            for (int i = 0; i < 4; ++i)
            #pragma unroll
            for (int j = 0; j < 4; ++j)
                acc[i][j] = __builtin_amdgcn_mfma_f32_16x16x32_bf16(af[i], bfr[j], acc[i][j], 0, 0, 0);
        }
    }
    float* Pz = P + (size_t)z * M * N;
    size_t rstride = ilv ? 1024 : (size_t)N;
    #pragma unroll
    for (int i = 0; i < 4; ++i)
    #pragma unroll
    for (int j = 0; j < 4; ++j) {
        int rr = m0 + wm + i * 16 + quad * 4;
        int cc = n0 + wn + j * 16 + lr;
        size_t base = ilv ? ((size_t)(rr & 2047) * 1024 + cc * 2 + (rr >> 11))
                          : ((size_t)rr * N + cc);
        float* cp = Pz + base;
        f32x4 v = acc[i][j];
        cp[0]           = v.x;
        cp[rstride]     = v.y;
        cp[2 * rstride] = v.z;
        cp[3 * rstride] = v.w;
    }
}

// Sum split-K partials: out[i] = alpha * sum_z P[z][i]  (layout-agnostic)
__global__ __launch_bounds__(256) void reduce_k(const float* __restrict__ P,
                                                float* __restrict__ out,
                                                int S, size_t elems, float alpha) {
    size_t idx = ((size_t)blockIdx.x * 256 + threadIdx.x) * 4;
    float4 s = *(const float4*)(P + idx);
    for (int zz = 1; zz < S; ++zz) {
        float4 v = *(const float4*)(P + (size_t)zz * elems + idx);
        s.x += v.x; s.y += v.y; s.z += v.z; s.w += v.w;
    }
    s.x *= alpha; s.y *= alpha; s.z *= alpha; s.w *= alpha;
    *(float4*)(out + idx) = s;
}

// ---------------------------------------------------------------------------
// Middle v4: fuses the forward split-K reduction (reads 4 P slices directly).
// g-tile 2, grid 1024 (4 blocks/CU). Thread owns channel pair (2p,2p+1) so
// weights come as one ds_read_b64; P is (re,im)-interleaved per slice so the
// summed row lands in sInc as float2 per channel.
__global__ __launch_bounds__(256, 4) void middle_k(const float* __restrict__ P,
                                                   const unsigned int* __restrict__ wt,
                                                   const float* __restrict__ phi_re,
                                                   const float* __restrict__ phi_im,
                                                   unsigned short* __restrict__ Yt) {
    __shared__ unsigned int sW[2][4096];   // 2 x 16 KB
    __shared__ float sInc[2][1024];        // 2 x 4 KB, interleaved (re,im) per c
    int t = threadIdx.x;
    int g0 = blockIdx.x * 2;
    int b = t >> 5, p = t & 31;

    #pragma unroll
    for (int gt = 0; gt < 2; ++gt) {
        int g = g0 + gt;
        #pragma unroll
        for (int j = 0; j < 4; ++j)
            ASYNC_COPY16(wt + (size_t)g * 4096 + (j * 256 + t) * 4, &sW[gt][(j * 256 + t) * 4]);
        // fused split-K reduce of forward GEMM partials (4 slices of 4096x512)
        float4 s = *(const float4*)(P + (size_t)g * 1024 + t * 4);
        #pragma unroll
        for (int z = 1; z < 4; ++z) {
            float4 pv = *(const float4*)(P + (size_t)z * 2097152 + (size_t)g * 1024 + t * 4);
            s.x += pv.x; s.y += pv.y; s.z += pv.z; s.w += pv.w;
        }
        *(float4*)(&sInc[gt][t * 4]) = s;
    }
    __syncthreads();

    unsigned short reA[2][2], imA[2][2];   // [ch][gt]

    #pragma unroll
    for (int gt = 0; gt < 2; ++gt) {
        int g = g0 + gt;
        float ar0 = 0.f, ai0 = 0.f, ar1 = 0.f, ai1 = 0.f;
        const float2* incp = (const float2*)sInc[gt] + b * 64;
        const unsigned int* wp = sW[gt] + 2 * p;
        #pragma unroll 8
        for (int i = 0; i < 64; ++i) {
            float2 a = incp[i];
            uint2 uu = *(const uint2*)(wp + i * 64);
            float w0r = __uint_as_float(uu.x << 16);
            float w0i = __uint_as_float(uu.x & 0xffff0000u);
            float w1r = __uint_as_float(uu.y << 16);
            float w1i = __uint_as_float(uu.y & 0xffff0000u);
            ar0 += a.x * w0r - a.y * w0i;  ai0 += a.x * w0i + a.y * w0r;
            ar1 += a.x * w1r - a.y * w1i;  ai1 += a.x * w1i + a.y * w1r;
        }
        float pr = phi_re[b * 2048 + g], pi = phi_im[b * 2048 + g];
        reA[0][gt] = f2bf(pr * ar0 - pi * ai0);
        imA[0][gt] = f2bf(pr * ai0 + pi * ar0);
        reA[1][gt] = f2bf(pr * ar1 - pi * ai1);
        imA[1][gt] = f2bf(pr * ai1 + pi * ar1);
    }

    #pragma unroll
    for (int ch = 0; ch < 2; ++ch) {
        int c = 2 * p + ch;
        size_t r0 = (size_t)(b * 64 + c) * 8192;
        size_t rf = (size_t)(b * 64 + 63 - c) * 8192;
        unsigned int ure = (unsigned int)reA[ch][0] | ((unsigned int)reA[ch][1] << 16);
        unsigned int uim = (unsigned int)imA[ch][0] | ((unsigned int)imA[ch][1] << 16);
        *(unsigned int*)(Yt + r0 + g0)        = ure;
        *(unsigned int*)(Yt + r0 + 2048 + g0) = uim;
        *(unsigned int*)(Yt + rf + 4096 + g0) = ure;
        *(unsigned int*)(Yt + rf + 6144 + g0) = uim;
    }
}

// ---------------------------------------------------------------------------
extern "C" void kernel_launch(void* const* d_in, const int* in_sizes, int n_in,
                              void* d_out, int out_size, void* d_ws, size_t ws_size,
                              hipStream_t stream) {
    const float* x     = (const float*)d_in[0];
    const float* emb   = (const float*)d_in[1];
    const float* vf_re = (const float*)d_in[2];
    const float* vf_im = (const float*)d_in[3];
    const float* vi_re = (const float*)d_in[4];
    const float* vi_im = (const float*)d_in[5];
    const float* w1_re = (const float*)d_in[6];
    const float* w1_im = (const float*)d_in[7];
    const float* w2_re = (const float*)d_in[8];
    const float* w2_im = (const float*)d_in[9];
    const float* m1_re = (const float*)d_in[10];
    const float* m1_im = (const float*)d_in[11];
    const float* m2_re = (const float*)d_in[12];
    const float* m2_im = (const float*)d_in[13];

    char* ws = (char*)d_ws;
    unsigned short* Af = (unsigned short*)(ws);                 // 16,777,216
    unsigned short* Xb = (unsigned short*)(ws + 16777216);      //  2,097,152
    unsigned short* Mi = (unsigned short*)(ws + 18874368);      // 33,554,432
    unsigned int*   Wt = (unsigned int*)(ws + 52428800);        // 33,554,432
    float*       PhiRe = (float*)(ws + 94371840);               //     65,536
    float*       PhiIm = (float*)(ws + 94437376);               //     65,536
    unsigned short* Yt = (unsigned short*)(ws + 94502912);      //  8,388,608
    float*          P  = (float*)(ws + 102891520);              // 33,554,432 partials
    float* out = (float*)d_out;

    pack_all<<<6400, 256, 0, stream>>>(vf_re, vf_im, x, vi_re, vi_im, Af, Xb, Mi);
    pack_wt<<<dim3(16, 64, 2), 256, 0, stream>>>(w1_re, w1_im, w2_re, w2_im, Wt);
    phi_k<<<2048, 256, 0, stream>>>(m1_re, m1_im, m2_re, m2_im, emb, PhiRe, PhiIm);

    // Forward: interleaved P[z] = Af[4096x2048] @ Xb[512x2048]^T, split-K 4
    gemm_sk<<<dim3(4, 32, 4), 256, 0, stream>>>(Af, Xb, P, 4096, 512, 2048, 512, 1);

    // middle fuses the 4-way split-K sum
    middle_k<<<1024, 256, 0, stream>>>(P, Wt, PhiRe, PhiIm, Yt);

    // Inverse: out[512][2048] = (2/N) * Yt[512x8192] @ Mi[2048x8192]^T, split-K 8
    gemm_sk<<<dim3(16, 4, 8), 256, 0, stream>>>(Yt, Mi, P, 512, 2048, 8192, 1024, 0);
    reduce_k<<<1024, 256, 0, stream>>>(P, out, 8, (size_t)512 * 2048, 1.0f / 1024.0f);
}

// Round 3
// 314.833 us; speedup vs baseline: 1.0152x; 1.0152x over previous
//
#include <hip/hip_runtime.h>

#define BB    8
#define CC    64
#define NN    2048
#define GG    2048
#define MFREQ 4032

typedef __attribute__((ext_vector_type(4))) float f32x4;
typedef __attribute__((ext_vector_type(8))) short bf16x8;

static __device__ __forceinline__ unsigned short f2bf(float f) {
    union { float f; unsigned u; } v; v.f = f;
    unsigned r = v.u + 0x7fff + ((v.u >> 16) & 1);   // RNE
    return (unsigned short)(r >> 16);
}

#define ASYNC_COPY16(gp, lp)                                                        \
    __builtin_amdgcn_global_load_lds(                                               \
        (const __attribute__((address_space(1))) unsigned int*)(gp),                \
        (__attribute__((address_space(3))) unsigned int*)(lp), 16, 0, 0)

// ---------------------------------------------------------------------------
// Merged prep: streaming packs + weight transpose + phi, one launch.
//  blocks [0, 2048)        : Af [4096 x 2048]
//  blocks [2048, 2304)     : Xb [512 x 2048]
//  blocks [2304, 6400)     : Mi [2048 x 8192]
//  blocks [6400, 14592)    : Wt transpose (32x32 LDS tiles, 8.4 KB)
//  blocks [14592, 16640)   : phi
__global__ __launch_bounds__(256) void prep_all(const float* __restrict__ vf_re,
                                                const float* __restrict__ vf_im,
                                                const float* __restrict__ x,
                                                const float* __restrict__ vi_re,
                                                const float* __restrict__ vi_im,
                                                const float* __restrict__ w1_re,
                                                const float* __restrict__ w1_im,
                                                const float* __restrict__ w2_re,
                                                const float* __restrict__ w2_im,
                                                const float* __restrict__ m1_re,
                                                const float* __restrict__ m1_im,
                                                const float* __restrict__ m2_re,
                                                const float* __restrict__ m2_im,
                                                const float* __restrict__ emb,
                                                unsigned short* __restrict__ af,
                                                unsigned short* __restrict__ xb,
                                                unsigned short* __restrict__ mi,
                                                unsigned int* __restrict__ wt,
                                                float* __restrict__ phi_re,
                                                float* __restrict__ phi_im) {
    __shared__ float sre[32][33];
    __shared__ float sim[32][33];
    __shared__ float sr4[4], si4[4];
    int blk = blockIdx.x;
    int t = threadIdx.x;

    if (blk < 6400) {
        // ---------------- streaming packs (round-2 form, verified) ----------
        float4 v[2][2];
        unsigned short* dst[2];
        if (blk < 2048) {
            #pragma unroll
            for (int u = 0; u < 2; ++u) {
                int gi = blk * 512 + u * 256 + t;
                int m = gi >> 8;
                int q8 = (gi & 255) * 8;
                int g = m & 2047;
                int f = (g >> 5) * 63 + (g & 31);
                const float* src = (m < 2048 ? vf_re : vf_im) + (size_t)f * 2048 + q8;
                v[u][0] = *(const float4*)src;
                v[u][1] = *(const float4*)(src + 4);
                dst[u] = af + (size_t)m * 2048 + q8;
            }
        } else if (blk < 2304) {
            #pragma unroll
            for (int u = 0; u < 2; ++u) {
                int gi = (blk - 2048) * 512 + u * 256 + t;
                int q8 = gi * 8;
                v[u][0] = *(const float4*)(x + q8);
                v[u][1] = *(const float4*)(x + q8 + 4);
                dst[u] = xb + q8;
            }
        } else {
            #pragma unroll
            for (int u = 0; u < 2; ++u) {
                int gi = (blk - 2304) * 512 + u * 256 + t;
                int n = gi >> 10;
                int q8 = (gi & 1023) * 8;
                int region = q8 >> 11;
                int off = q8 & 2047;
                if (region == 0) {
                    const float* src = vi_re + (size_t)n * MFREQ + off;
                    v[u][0] = *(const float4*)src;
                    v[u][1] = *(const float4*)(src + 4);
                } else if (region == 1) {
                    const float* src = vi_im + (size_t)n * MFREQ + off;
                    float4 a = *(const float4*)src;
                    float4 b = *(const float4*)(src + 4);
                    v[u][0].x = -a.x; v[u][0].y = -a.y; v[u][0].z = -a.z; v[u][0].w = -a.w;
                    v[u][1].x = -b.x; v[u][1].y = -b.y; v[u][1].z = -b.z; v[u][1].w = -b.w;
                } else {
                    if (off < 64) {
                        v[u][0].x = v[u][0].y = v[u][0].z = v[u][0].w = 0.0f;
                        v[u][1].x = v[u][1].y = v[u][1].z = v[u][1].w = 0.0f;
                    } else {
                        const float* src = (region == 2 ? vi_re : vi_im) + (size_t)n * MFREQ;
                        float4 a = *(const float4*)(src + 4092 - off);
                        float4 b = *(const float4*)(src + 4088 - off);
                        v[u][0].x = a.w; v[u][0].y = a.z; v[u][0].z = a.y; v[u][0].w = a.x;
                        v[u][1].x = b.w; v[u][1].y = b.z; v[u][1].z = b.y; v[u][1].w = b.x;
                    }
                }
                dst[u] = mi + (size_t)n * 8192 + q8;
            }
        }
        #pragma unroll
        for (int u = 0; u < 2; ++u) {
            uint4 o;
            o.x = (unsigned int)f2bf(v[u][0].x) | ((unsigned int)f2bf(v[u][0].y) << 16);
            o.y = (unsigned int)f2bf(v[u][0].z) | ((unsigned int)f2bf(v[u][0].w) << 16);
            o.z = (unsigned int)f2bf(v[u][1].x) | ((unsigned int)f2bf(v[u][1].y) << 16);
            o.w = (unsigned int)f2bf(v[u][1].z) | ((unsigned int)f2bf(v[u][1].w) << 16);
            *(uint4*)dst[u] = o;
        }
    } else if (blk < 14592) {
        // ---------------- weight transpose, 32x32 tiles ---------------------
        int bi = blk - 6400;             // [0, 8192)
        int wsel = bi >> 12;             // 4096 tiles per w
        int bj = bi & 4095;
        int io0 = (bj >> 5) * 32;        // 128 io-tiles
        int xy0 = (bj & 31) * 32;        // 32 xy-tiles
        const float* wre = wsel ? w2_re : w1_re;
        const float* wim = wsel ? w2_im : w1_im;
        int r = t >> 3, c4 = (t & 7) * 4;
        float4 a = *(const float4*)(wre + (size_t)(io0 + r) * 1024 + xy0 + c4);
        float4 b = *(const float4*)(wim + (size_t)(io0 + r) * 1024 + xy0 + c4);
        sre[r][c4 + 0] = a.x; sre[r][c4 + 1] = a.y; sre[r][c4 + 2] = a.z; sre[r][c4 + 3] = a.w;
        sim[r][c4 + 0] = b.x; sim[r][c4 + 1] = b.y; sim[r][c4 + 2] = b.z; sim[r][c4 + 3] = b.w;
        __syncthreads();
        int gr = t >> 3, ic4 = (t & 7) * 4;
        uint4 o;
        o.x = (unsigned int)f2bf(sre[ic4 + 0][gr]) | ((unsigned int)f2bf(sim[ic4 + 0][gr]) << 16);
        o.y = (unsigned int)f2bf(sre[ic4 + 1][gr]) | ((unsigned int)f2bf(sim[ic4 + 1][gr]) << 16);
        o.z = (unsigned int)f2bf(sre[ic4 + 2][gr]) | ((unsigned int)f2bf(sim[ic4 + 2][gr]) << 16);
        o.w = (unsigned int)f2bf(sre[ic4 + 3][gr]) | ((unsigned int)f2bf(sim[ic4 + 3][gr]) << 16);
        int g = xy0 + gr + wsel * 1024;
        *(uint4*)(wt + (size_t)g * 4096 + io0 + ic4) = o;
    } else {
        // ---------------- phi ----------------------------------------------
        int g = blk - 14592, e = t;
        int xy = g & 1023;
        const float* mr = (g < 1024 ? m1_re : m2_re) + xy * 256;
        const float* mp = (g < 1024 ? m1_im : m2_im) + xy * 256;
        float vr = mr[e], vi = mp[e];
        for (int bb = 0; bb < 8; ++bb) {
            float em = emb[bb * 256 + e];
            float pr = vr * em, pi = vi * em;
            for (int s = 32; s > 0; s >>= 1) { pr += __shfl_down(pr, s); pi += __shfl_down(pi, s); }
            int wid = e >> 6;
            if ((e & 63) == 0) { sr4[wid] = pr; si4[wid] = pi; }
            __syncthreads();
            if (e == 0) {
                phi_re[bb * 2048 + g] = sr4[0] + sr4[1] + sr4[2] + sr4[3];
                phi_im[bb * 2048 + g] = si4[0] + si4[1] + si4[2] + si4[3];
            }
            __syncthreads();
        }
    }
}

// ---------------------------------------------------------------------------
// Split-K MFMA GEMM, tile TM x TM (TM in {64,128}): P[z] = A @ B^T slice.
// ilv=1 (forward): store element (rr,cc) at ((rr&2047)*1024 + cc*2 + (rr>>11)),
// i.e. O1 interleaved as [g][c][{re,im}] so middle can ds_read_b64 float2.
template<int TM>
__global__ __launch_bounds__(256, 2) void gemm_sk(const unsigned short* __restrict__ A,
                                                  const unsigned short* __restrict__ Bm,
                                                  float* __restrict__ P,
                                                  int M, int N, int K, int Kper, int ilv) {
    constexpr int FI = TM / 32;          // frags per wave dim; staging copies
    __shared__ unsigned short As[TM * 64];
    __shared__ unsigned short Bs[TM * 64];
    int t = threadIdx.x;
    int lane = t & 63, w = t >> 6;
    int m0 = blockIdx.y * TM, n0 = blockIdx.x * TM;
    int z = blockIdx.z;
    int kbase = z * Kper;
    int wm = (w >> 1) * (TM / 2), wn = (w & 1) * (TM / 2);
    int lr = lane & 15, quad = lane >> 4;
    int rsub = lane >> 3, slot = lane & 7;

    f32x4 acc[FI][FI] = {};

    for (int kk = kbase; kk < kbase + Kper; kk += 64) {
        __syncthreads();
        #pragma unroll
        for (int l = 0; l < FI; ++l) {
            int r = (w * FI + l) * 8 + rsub;
            int c = slot ^ (r & 7);
            ASYNC_COPY16(A + (size_t)(m0 + r) * K + kk + c * 8, As + r * 64 + slot * 8);
            ASYNC_COPY16(Bm + (size_t)(n0 + r) * K + kk + c * 8, Bs + r * 64 + slot * 8);
        }
        __syncthreads();
        #pragma unroll
        for (int ks = 0; ks < 2; ++ks) {
            bf16x8 af[FI], bfr[FI];
            #pragma unroll
            for (int i = 0; i < FI; ++i) {
                int row = wm + i * 16 + lr;
                int q = (ks * 4 + quad) ^ (row & 7);
                af[i] = *(const bf16x8*)(As + row * 64 + q * 8);
                int rowb = wn + i * 16 + lr;
                int qb = (ks * 4 + quad) ^ (rowb & 7);
                bfr[i] = *(const bf16x8*)(Bs + rowb * 64 + qb * 8);
            }
            #pragma unroll
            for (int i = 0; i < FI; ++i)
            #pragma unroll
            for (int j = 0; j < FI; ++j)
                acc[i][j] = __builtin_amdgcn_mfma_f32_16x16x32_bf16(af[i], bfr[j], acc[i][j], 0, 0, 0);
        }
    }
    float* Pz = P + (size_t)z * M * N;
    size_t rstride = ilv ? 1024 : (size_t)N;
    #pragma unroll
    for (int i = 0; i < FI; ++i)
    #pragma unroll
    for (int j = 0; j < FI; ++j) {
        int rr = m0 + wm + i * 16 + quad * 4;
        int cc = n0 + wn + j * 16 + lr;
        size_t base = ilv ? ((size_t)(rr & 2047) * 1024 + cc * 2 + (rr >> 11))
                          : ((size_t)rr * N + cc);
        float* cp = Pz + base;
        f32x4 v = acc[i][j];
        cp[0]           = v.x;
        cp[rstride]     = v.y;
        cp[2 * rstride] = v.z;
        cp[3 * rstride] = v.w;
    }
}

// Sum split-K partials: out[i] = alpha * sum_z P[z][i]  (layout-agnostic)
__global__ __launch_bounds__(256) void reduce_k(const float* __restrict__ P,
                                                float* __restrict__ out,
                                                int S, size_t elems, float alpha) {
    size_t idx = ((size_t)blockIdx.x * 256 + threadIdx.x) * 4;
    float4 s = *(const float4*)(P + idx);
    for (int zz = 1; zz < S; ++zz) {
        float4 v = *(const float4*)(P + (size_t)zz * elems + idx);
        s.x += v.x; s.y += v.y; s.z += v.z; s.w += v.w;
    }
    s.x *= alpha; s.y *= alpha; s.z *= alpha; s.w *= alpha;
    *(float4*)(out + idx) = s;
}

// ---------------------------------------------------------------------------
// Middle v5: forward GEMM writes O1 directly (no split-K), so stage O1 rows
// straight to LDS via global_load_lds. g-tile 2, grid 1024 (4 blocks/CU).
__global__ __launch_bounds__(256, 4) void middle_k(const float* __restrict__ O1,
                                                   const unsigned int* __restrict__ wt,
                                                   const float* __restrict__ phi_re,
                                                   const float* __restrict__ phi_im,
                                                   unsigned short* __restrict__ Yt) {
    __shared__ unsigned int sW[2][4096];   // 2 x 16 KB
    __shared__ float sInc[2][1024];        // 2 x 4 KB, interleaved (re,im) per c
    int t = threadIdx.x;
    int g0 = blockIdx.x * 2;
    int b = t >> 5, p = t & 31;

    #pragma unroll
    for (int gt = 0; gt < 2; ++gt) {
        int g = g0 + gt;
        #pragma unroll
        for (int j = 0; j < 4; ++j)
            ASYNC_COPY16(wt + (size_t)g * 4096 + (j * 256 + t) * 4, &sW[gt][(j * 256 + t) * 4]);
        ASYNC_COPY16(O1 + (size_t)g * 1024 + t * 4, &sInc[gt][t * 4]);
    }
    __syncthreads();

    unsigned short reA[2][2], imA[2][2];   // [ch][gt]

    #pragma unroll
    for (int gt = 0; gt < 2; ++gt) {
        int g = g0 + gt;
        float ar0 = 0.f, ai0 = 0.f, ar1 = 0.f, ai1 = 0.f;
        const float2* incp = (const float2*)sInc[gt] + b * 64;
        const unsigned int* wp = sW[gt] + 2 * p;
        #pragma unroll 8
        for (int i = 0; i < 64; ++i) {
            float2 a = incp[i];
            uint2 uu = *(const uint2*)(wp + i * 64);
            float w0r = __uint_as_float(uu.x << 16);
            float w0i = __uint_as_float(uu.x & 0xffff0000u);
            float w1r = __uint_as_float(uu.y << 16);
            float w1i = __uint_as_float(uu.y & 0xffff0000u);
            ar0 += a.x * w0r - a.y * w0i;  ai0 += a.x * w0i + a.y * w0r;
            ar1 += a.x * w1r - a.y * w1i;  ai1 += a.x * w1i + a.y * w1r;
        }
        float pr = phi_re[b * 2048 + g], pi = phi_im[b * 2048 + g];
        reA[0][gt] = f2bf(pr * ar0 - pi * ai0);
        imA[0][gt] = f2bf(pr * ai0 + pi * ar0);
        reA[1][gt] = f2bf(pr * ar1 - pi * ai1);
        imA[1][gt] = f2bf(pr * ai1 + pi * ar1);
    }

    #pragma unroll
    for (int ch = 0; ch < 2; ++ch) {
        int c = 2 * p + ch;
        size_t r0 = (size_t)(b * 64 + c) * 8192;
        size_t rf = (size_t)(b * 64 + 63 - c) * 8192;
        unsigned int ure = (unsigned int)reA[ch][0] | ((unsigned int)reA[ch][1] << 16);
        unsigned int uim = (unsigned int)imA[ch][0] | ((unsigned int)imA[ch][1] << 16);
        *(unsigned int*)(Yt + r0 + g0)        = ure;
        *(unsigned int*)(Yt + r0 + 2048 + g0) = uim;
        *(unsigned int*)(Yt + rf + 4096 + g0) = ure;
        *(unsigned int*)(Yt + rf + 6144 + g0) = uim;
    }
}

// ---------------------------------------------------------------------------
extern "C" void kernel_launch(void* const* d_in, const int* in_sizes, int n_in,
                              void* d_out, int out_size, void* d_ws, size_t ws_size,
                              hipStream_t stream) {
    const float* x     = (const float*)d_in[0];
    const float* emb   = (const float*)d_in[1];
    const float* vf_re = (const float*)d_in[2];
    const float* vf_im = (const float*)d_in[3];
    const float* vi_re = (const float*)d_in[4];
    const float* vi_im = (const float*)d_in[5];
    const float* w1_re = (const float*)d_in[6];
    const float* w1_im = (const float*)d_in[7];
    const float* w2_re = (const float*)d_in[8];
    const float* w2_im = (const float*)d_in[9];
    const float* m1_re = (const float*)d_in[10];
    const float* m1_im = (const float*)d_in[11];
    const float* m2_re = (const float*)d_in[12];
    const float* m2_im = (const float*)d_in[13];

    char* ws = (char*)d_ws;
    unsigned short* Af = (unsigned short*)(ws);                 // 16,777,216
    unsigned short* Xb = (unsigned short*)(ws + 16777216);      //  2,097,152
    unsigned short* Mi = (unsigned short*)(ws + 18874368);      // 33,554,432
    unsigned int*   Wt = (unsigned int*)(ws + 52428800);        // 33,554,432
    float*          O1 = (float*)(ws + 85983232);               //  8,388,608 (interleaved re,im)
    float*       PhiRe = (float*)(ws + 94371840);               //     65,536
    float*       PhiIm = (float*)(ws + 94437376);               //     65,536
    unsigned short* Yt = (unsigned short*)(ws + 94502912);      //  8,388,608
    float*          P  = (float*)(ws + 102891520);              // 33,554,432 partials
    float* out = (float*)d_out;

    prep_all<<<16640, 256, 0, stream>>>(vf_re, vf_im, x, vi_re, vi_im,
                                        w1_re, w1_im, w2_re, w2_im,
                                        m1_re, m1_im, m2_re, m2_im, emb,
                                        Af, Xb, Mi, Wt, PhiRe, PhiIm);

    // Forward: O1 (interleaved) = Af[4096x2048] @ Xb[512x2048]^T, 64^2 tiles,
    // full-K (no split-K, no partials, no reduce)
    gemm_sk<64><<<dim3(8, 64, 1), 256, 0, stream>>>(Af, Xb, O1, 4096, 512, 2048, 2048, 1);

    middle_k<<<1024, 256, 0, stream>>>(O1, Wt, PhiRe, PhiIm, Yt);

    // Inverse: out[512][2048] = (2/N) * Yt[512x8192] @ Mi[2048x8192]^T, split-K 8
    gemm_sk<128><<<dim3(16, 4, 8), 256, 0, stream>>>(Yt, Mi, P, 512, 2048, 8192, 1024, 0);
    reduce_k<<<1024, 256, 0, stream>>>(P, out, 8, (size_t)512 * 2048, 1.0f / 1024.0f);
}